// Round 2
// baseline (4156.258 us; speedup 1.0000x reference)
//
#include <hip/hip_runtime.h>

namespace {

constexpr int T_STEPS = 32;
constexpr int BATCH   = 8192;
constexpr int H1      = 480;   // first dense layer
constexpr int HID     = 200;   // GRU hidden
constexpr int G3      = 600;   // 3*HID
constexpr int H2      = 320;   // second dense layer
constexpr int BR      = 16;    // batch rows per block
constexpr int NTHR    = 256;   // threads per block

__device__ __forceinline__ float sigmoid_(float x) {
    return 1.f / (1.f + __expf(-x));
}

__device__ __forceinline__ float tanh_(float x) {
    x = fminf(fmaxf(x, -15.f), 15.f);
    const float e = __expf(-2.f * x);
    return (1.f - e) / (1.f + e);
}

// read 16 contiguous floats from LDS via 4x ds_read_b128 (same addr across
// lanes -> broadcast, no bank conflicts)
__device__ __forceinline__ void load16(const float* __restrict__ p, float* a) {
    const float4* v = reinterpret_cast<const float4*>(p);
#pragma unroll
    for (int q = 0; q < 4; ++q) {
        const float4 t = v[q];
        a[4 * q + 0] = t.x;
        a[4 * q + 1] = t.y;
        a[4 * q + 2] = t.z;
        a[4 * q + 3] = t.w;
    }
}

__global__ __launch_bounds__(NTHR, 2) void knet_kernel(
    const float* __restrict__ y,    // [T,B,2]
    const float* __restrict__ Fm,   // [4,4]
    const float* __restrict__ Hm,   // [2,4]
    const float* __restrict__ W1,   // [8,480]
    const float* __restrict__ b1,   // [480]
    const float* __restrict__ Wg,   // [480,600]
    const float* __restrict__ Ug,   // [200,600]
    const float* __restrict__ bg,   // [2,600]
    const float* __restrict__ W2,   // [200,320]
    const float* __restrict__ b2,   // [320]
    const float* __restrict__ W3,   // [320,8]
    const float* __restrict__ b3,   // [8]
    const float* __restrict__ hn0,  // [B,200]
    float* __restrict__ out)        // [T,B,4]
{
    // transposed activation tiles: [feature][row] so per-k reads are 16
    // contiguous floats (broadcast across lanes)
    __shared__ float s_hnt[2][HID][BR];  // double-buffered GRU state
    __shared__ float s_a1t[H1][BR];
    __shared__ float s_a2t[H2][BR];
    __shared__ float s_in8[BR][8];
    __shared__ float s_dm1y[BR][2];
    __shared__ float s_prior[BR][4];
    __shared__ float s_post[BR][4];
    __shared__ float s_kg[BR][8];

    const int tid  = threadIdx.x;
    const int row0 = blockIdx.x * BR;  // global batch row base

    // ---- init: hn0 -> s_hnt[0] (transpose), zero prior/post ----
    for (int idx = tid; idx < BR * HID; idx += NTHR) {
        const int r = idx / HID;
        const int k = idx - r * HID;  // coalesced global read per row
        s_hnt[0][k][r] = hn0[(size_t)(row0 + r) * HID + k];
    }
    if (tid < BR * 4) {
        s_prior[tid >> 2][tid & 3] = 0.f;
        s_post[tid >> 2][tid & 3]  = 0.f;
    }
    __syncthreads();

    int cur = 0;
    for (int t = 0; t < T_STEPS; ++t) {
        const int nxt = cur ^ 1;

        // ---- Phase A: per-row prior/innovation/features ----
        if (tid < BR) {
            const int r = tid;
            float post[4], prevpri[4], pri[4];
#pragma unroll
            for (int m = 0; m < 4; ++m) {
                post[m]    = s_post[r][m];
                prevpri[m] = s_prior[r][m];
            }
#pragma unroll
            for (int m = 0; m < 4; ++m) {
                float s = 0.f;
#pragma unroll
                for (int j = 0; j < 4; ++j) s += Fm[m * 4 + j] * post[j];
                pri[m] = s;
            }
            float dy[2];
#pragma unroll
            for (int n = 0; n < 2; ++n) {
                float s = 0.f;
#pragma unroll
                for (int m = 0; m < 4; ++m) s += Hm[n * 4 + m] * pri[m];
                dy[n] = y[((size_t)t * BATCH + row0 + r) * 2 + n] - s;
            }
            float dx[4], ssx = 0.f;
#pragma unroll
            for (int m = 0; m < 4; ++m) {
                dx[m] = post[m] - prevpri[m];
                ssx += dx[m] * dx[m];
            }
            const float idx_ = rsqrtf(fmaxf(ssx, 1e-12f));
            const float ssy  = dy[0] * dy[0] + dy[1] * dy[1];
            const float idy_ = rsqrtf(fmaxf(ssy, 1e-12f));
            // knet_in = [dm1y_norm, dm1y_norm, dm1x_norm]
            s_in8[r][0] = dy[0] * idy_;
            s_in8[r][1] = dy[1] * idy_;
            s_in8[r][2] = dy[0] * idy_;
            s_in8[r][3] = dy[1] * idy_;
#pragma unroll
            for (int m = 0; m < 4; ++m) s_in8[r][4 + m] = dx[m] * idx_;
            s_dm1y[r][0] = dy[0];
            s_dm1y[r][1] = dy[1];
#pragma unroll
            for (int m = 0; m < 4; ++m) s_prior[r][m] = pri[m];
        }
        __syncthreads();

        // ---- Phase B: a1t[j][r] = relu(b1[j] + sum_k in8[r][k]*W1[k][j]) ----
        for (int idx = tid; idx < H1 * BR; idx += NTHR) {
            const int r = idx & (BR - 1);
            const int j = idx >> 4;
            float s = b1[j];
#pragma unroll
            for (int k = 0; k < 8; ++k) s = fmaf(s_in8[r][k], W1[k * H1 + j], s);
            s_a1t[j][r] = fmaxf(s, 0.f);
        }
        __syncthreads();

        // ---- Phase C: fused GRU. thread j owns column j for all 16 rows ----
        if (tid < HID) {
            const int j = tid;
            float az[BR], ar_[BR], ahx[BR], ahh[BR];
#pragma unroll
            for (int r = 0; r < BR; ++r) { az[r] = 0.f; ar_[r] = 0.f; ahx[r] = 0.f; ahh[r] = 0.f; }

            const float* wg = Wg + j;
            for (int k = 0; k < H1; ++k) {
                const float wz = wg[k * G3];
                const float wr = wg[k * G3 + HID];
                const float wh = wg[k * G3 + 2 * HID];
                float a[BR];
                load16(&s_a1t[k][0], a);
#pragma unroll
                for (int r = 0; r < BR; ++r) {
                    az[r]  = fmaf(a[r], wz, az[r]);
                    ar_[r] = fmaf(a[r], wr, ar_[r]);
                    ahx[r] = fmaf(a[r], wh, ahx[r]);
                }
            }
            const float* ug = Ug + j;
            for (int k = 0; k < HID; ++k) {
                const float uz = ug[k * G3];
                const float ur = ug[k * G3 + HID];
                const float uh = ug[k * G3 + 2 * HID];
                float h[BR];
                load16(&s_hnt[cur][k][0], h);
#pragma unroll
                for (int r = 0; r < BR; ++r) {
                    az[r]  = fmaf(h[r], uz, az[r]);
                    ar_[r] = fmaf(h[r], ur, ar_[r]);
                    ahh[r] = fmaf(h[r], uh, ahh[r]);
                }
            }
            // biases: z/r can fold input+recurrent; hcand cannot (r scales hh bias)
            const float bz  = bg[j] + bg[G3 + j];
            const float brr = bg[HID + j] + bg[G3 + HID + j];
            const float bhx = bg[2 * HID + j];
            const float bhh = bg[G3 + 2 * HID + j];
#pragma unroll
            for (int r = 0; r < BR; ++r) {
                const float z  = sigmoid_(az[r] + bz);
                const float rr = sigmoid_(ar_[r] + brr);
                const float hc = tanh_((ahx[r] + bhx) + rr * (ahh[r] + bhh));
                const float ho = s_hnt[cur][j][r];
                s_hnt[nxt][j][r] = z * ho + (1.f - z) * hc;
            }
        }
        __syncthreads();

        // ---- Phase D: a2t[j][r] = relu(b2[j] + hn_new . W2[:,j]) ----
        for (int j = tid; j < H2; j += NTHR) {
            float acc[BR];
#pragma unroll
            for (int r = 0; r < BR; ++r) acc[r] = 0.f;
            for (int k = 0; k < HID; ++k) {
                const float w = W2[k * H2 + j];
                float h[BR];
                load16(&s_hnt[nxt][k][0], h);
#pragma unroll
                for (int r = 0; r < BR; ++r) acc[r] = fmaf(h[r], w, acc[r]);
            }
            const float bb = b2[j];
#pragma unroll
            for (int r = 0; r < BR; ++r) s_a2t[j][r] = fmaxf(acc[r] + bb, 0.f);
        }
        __syncthreads();

        // ---- Phase E: KG[r][c] = b3[c] + a2 . W3[:,c]  (128 items) ----
        if (tid < BR * 8) {
            const int r = tid >> 3;
            const int c = tid & 7;
            float acc = b3[c];
            for (int k = 0; k < H2; ++k) acc = fmaf(s_a2t[k][r], W3[k * 8 + c], acc);
            s_kg[r][c] = acc;
        }
        __syncthreads();

        // ---- Phase F: innovation, posterior update, output write ----
        if (tid < BR) {
            const int r   = tid;
            const float d0 = s_dm1y[r][0];
            const float d1 = s_dm1y[r][1];
#pragma unroll
            for (int m = 0; m < 4; ++m) {
                const float inov = s_kg[r][2 * m] * d0 + s_kg[r][2 * m + 1] * d1;
                const float p    = s_prior[r][m] + inov;
                s_post[r][m]     = p;
                out[((size_t)t * BATCH + row0 + r) * 4 + m] = p;
            }
        }
        cur = nxt;
        __syncthreads();
    }
}

}  // namespace

extern "C" void kernel_launch(void* const* d_in, const int* in_sizes, int n_in,
                              void* d_out, int out_size, void* d_ws, size_t ws_size,
                              hipStream_t stream) {
    const float* y   = (const float*)d_in[0];
    const float* Fm  = (const float*)d_in[1];
    const float* Hm  = (const float*)d_in[2];
    const float* W1  = (const float*)d_in[3];
    const float* b1  = (const float*)d_in[4];
    const float* Wg  = (const float*)d_in[5];
    const float* Ug  = (const float*)d_in[6];
    const float* bg  = (const float*)d_in[7];
    const float* W2  = (const float*)d_in[8];
    const float* b2  = (const float*)d_in[9];
    const float* W3  = (const float*)d_in[10];
    const float* b3  = (const float*)d_in[11];
    const float* hn0 = (const float*)d_in[12];
    float* out = (float*)d_out;

    dim3 grid(BATCH / BR);   // 512 blocks, 2 per CU
    dim3 block(NTHR);
    knet_kernel<<<grid, block, 0, stream>>>(y, Fm, Hm, W1, b1, Wg, Ug, bg,
                                            W2, b2, W3, b3, hn0, out);
}